// Round 6
// baseline (501.849 us; speedup 1.0000x reference)
//
#include <hip/hip_runtime.h>

typedef unsigned short u16;
typedef unsigned int u32;
typedef __bf16 bf16;
typedef bf16 bf16x8 __attribute__((ext_vector_type(8)));
typedef float f32x4 __attribute__((ext_vector_type(4)));
typedef u32 u32x4 __attribute__((ext_vector_type(4)));

#define EMBED 1024
#define HEADS 16
#define HS 64
#define BATCH 2
#define SEQ 2048
#define M_TOT (BATCH * SEQ)   // 4096
#define N_QKV (3 * EMBED)     // 3072
#define KDIM  EMBED           // 1024

// softmax scale folded into exp2: (1/sqrt(64)) * log2(e)
#define CSCALE 0.18033688011112042f

__device__ __forceinline__ u16 f2bf(float f) {
  u32 u = __builtin_bit_cast(u32, f);
  u32 r = u + 0x7fffu + ((u >> 16) & 1u);
  return (u16)(r >> 16);
}
__device__ __forceinline__ float bf2f(u16 h) {
  return __builtin_bit_cast(float, (u32)h << 16);
}
__device__ __forceinline__ bf16x8 frag16(const u16* p) {
  return __builtin_bit_cast(bf16x8, *(const u32x4*)p);
}
__device__ __forceinline__ bf16x8 frag16u(const u32* p) {
  return __builtin_bit_cast(bf16x8, *(const u32x4*)p);
}
// NaN-squashing clamp (diagnostic insurance): cl(NaN) = -3e4.
__device__ __forceinline__ float cl(float v) {
  return fminf(fmaxf(v, -3.0e4f), 3.0e4f);
}

// ---- input dtype detection (f32 vs bf16); inputs confirmed f32 (r3->r4) ----
__device__ bool detect_bf16(const u32* p) {
  int ok = 0;
#pragma unroll 1
  for (int i = 0; i < 256; i++) {
    u32 w = p[i];
    u32 e = (w >> 7) & 0xFFu;
    ok += ((e >= 90u) && (e <= 150u)) || ((w & 0x7FFFu) == 0u) ? 1 : 0;
  }
  return ok == 256;
}

__global__ __launch_bounds__(256) void convert_kernel(
    const void* __restrict__ in, u16* __restrict__ out, int n) {
  __shared__ int s_isbf;
  if (threadIdx.x == 0) s_isbf = detect_bf16((const u32*)in) ? 1 : 0;
  __syncthreads();
  const bool isbf = (s_isbf != 0);
  const int i = blockIdx.x * 256 + threadIdx.x;
  if (i < n)
    out[i] = isbf ? ((const u16*)in)[i] : f2bf(((const float*)in)[i]);
}

__global__ __launch_bounds__(256) void transpose_conv_kernel(
    const void* __restrict__ in, u16* __restrict__ out, int R, int C) {
  __shared__ u16 tile[32][33];
  __shared__ int s_isbf;
  if (threadIdx.x == 0 && threadIdx.y == 0)
    s_isbf = detect_bf16((const u32*)in) ? 1 : 0;
  __syncthreads();
  const bool isbf = (s_isbf != 0);
  const int c0 = blockIdx.x * 32;
  const int r0 = blockIdx.y * 32;
  const int tx = threadIdx.x;
  const int ty = threadIdx.y;
#pragma unroll
  for (int i = 0; i < 32; i += 8) {
    const size_t idx = (size_t)(r0 + ty + i) * C + c0 + tx;
    tile[ty + i][tx] = isbf ? ((const u16*)in)[idx] : f2bf(((const float*)in)[idx]);
  }
  __syncthreads();
#pragma unroll
  for (int i = 0; i < 32; i += 8)
    out[(size_t)(c0 + ty + i) * R + r0 + tx] = tile[tx][ty + i];
}

// ---------------- GEMM: out[4096][N] = A[4096][1024] @ Wt[N][1024]^T + bias
// F32OUT: write float (final output buffer is f32!), else bf16.
template <bool F32OUT>
__global__ __launch_bounds__(256) void gemm_bt_kernel(
    const u16* __restrict__ A, const u16* __restrict__ wt,
    const u16* __restrict__ bias, void* __restrict__ outv, int N) {
  __shared__ u16 As[128 * 32];
  __shared__ u16 Bs[128 * 32];
  const int tid = threadIdx.x;
  const int lane = tid & 63;
  const int wave = tid >> 6;
  const int quad = lane >> 4;
  const int l16 = lane & 15;
  const int wr = wave >> 1;
  const int wc = wave & 1;
  const int m0 = blockIdx.y * 128;
  const int n0 = blockIdx.x * 128;

  f32x4 acc[4][4] = {};

  const int arow = tid >> 2;
  const int agrp = (tid & 3) * 8;

  for (int k0 = 0; k0 < KDIM; k0 += 32) {
    __syncthreads();
    u32x4 a0 = *(const u32x4*)(A + (size_t)(m0 + arow) * KDIM + k0 + agrp);
    u32x4 a1 = *(const u32x4*)(A + (size_t)(m0 + arow + 64) * KDIM + k0 + agrp);
    u32x4 b0 = *(const u32x4*)(wt + (size_t)(n0 + arow) * KDIM + k0 + agrp);
    u32x4 b1 = *(const u32x4*)(wt + (size_t)(n0 + arow + 64) * KDIM + k0 + agrp);
    *(u32x4*)(As + arow * 32 + agrp) = a0;
    *(u32x4*)(As + (arow + 64) * 32 + agrp) = a1;
    *(u32x4*)(Bs + arow * 32 + agrp) = b0;
    *(u32x4*)(Bs + (arow + 64) * 32 + agrp) = b1;
    __syncthreads();

    bf16x8 af[4], bfr[4];
#pragma unroll
    for (int i = 0; i < 4; i++) {
      af[i]  = frag16(As + (wr * 64 + i * 16 + l16) * 32 + quad * 8);
      bfr[i] = frag16(Bs + (wc * 64 + i * 16 + l16) * 32 + quad * 8);
    }
#pragma unroll
    for (int mi = 0; mi < 4; mi++)
#pragma unroll
      for (int ni = 0; ni < 4; ni++)
        acc[mi][ni] = __builtin_amdgcn_mfma_f32_16x16x32_bf16(
            af[mi], bfr[ni], acc[mi][ni], 0, 0, 0);
  }

#pragma unroll
  for (int ni = 0; ni < 4; ni++) {
    const int n = n0 + wc * 64 + ni * 16 + l16;
    const float bv = bf2f(bias[n]);
#pragma unroll
    for (int mi = 0; mi < 4; mi++) {
#pragma unroll
      for (int r = 0; r < 4; r++) {
        const int m = m0 + wr * 64 + mi * 16 + quad * 4 + r;
        const float v = cl(acc[mi][ni][r] + bv);
        if (F32OUT) ((float*)outv)[(size_t)m * N + n] = v;
        else        ((u16*)outv)[(size_t)m * N + n] = f2bf(v);
      }
    }
  }
}

// ---------------- flash attention (S^T / O^T formulation), causal --------
// qkv packed [4096][3072]: k=[0,1024) q=[1024,2048) v=[2048,3072) (k FIRST).
// S^T = K.Q^T  (C-layout: row=key, col=q=l16) -> per-lane scalar m,l (q fixed/lane)
// O^T = V^T.P^T (A=V^T LDS [d][keypair], B=P^T per-wave LDS [q][keypair])
// Verified by r4/r5 cross-implementation agreement.
__global__ __launch_bounds__(256) void attn_kernel(
    const u16* __restrict__ qkv, u16* __restrict__ att) {
  __shared__ u16 Ks[32 * 64];      // [key][d]
  __shared__ u32 Vs32[64 * 16];    // [d][keypair]
  __shared__ u32 Ps32[4][16 * 16]; // per-wave: [q][keypair]

  const int tid = threadIdx.x;
  const int lane = tid & 63;
  const int wave = tid >> 6;
  const int quad = lane >> 4;
  const int l16 = lane & 15;

  const int qt = blockIdx.x;        // 0..31
  const int bh = blockIdx.y;        // 0..31
  const int q0 = qt * 64;
  const int bq = bh >> 4;
  const int h = bh & 15;

  const int koff = h * HS;
  const int qoff = EMBED + h * HS;
  const int voff = 2 * EMBED + h * HS;

  const int q = q0 + wave * 16 + l16;
  const size_t qrow = (size_t)(bq * SEQ + q) * N_QKV;

  bf16x8 bq0 = frag16(qkv + qrow + qoff + quad * 8);
  bf16x8 bq1 = frag16(qkv + qrow + qoff + 32 + quad * 8);

  float m_old = -1e30f, lsum = 0.0f;
  f32x4 o[4] = {};   // O^T C-layout: row=d(dc*16+quad*4+r), col=q(l16)

  const int nkt = qt * 2 + 2;
  for (int kt = 0; kt < nkt; kt++) {
    const int k0 = kt * 32;
    __syncthreads();
    {
      const int key = tid >> 3, d8 = (tid & 7) * 8;
      *(u32x4*)(Ks + key * 64 + d8) =
          *(const u32x4*)(qkv + (size_t)(bq * SEQ + k0 + key) * N_QKV + koff + d8);
    }
    {
      const int d = tid >> 2, kpb = (tid & 3) * 4;
#pragma unroll
      for (int i = 0; i < 4; i++) {
        const int kp = kpb + i;
        const u32 lo = qkv[(size_t)(bq * SEQ + k0 + 2 * kp) * N_QKV + voff + d];
        const u32 hi = qkv[(size_t)(bq * SEQ + k0 + 2 * kp + 1) * N_QKV + voff + d];
        Vs32[d * 16 + kp] = lo | (hi << 16);
      }
    }
    __syncthreads();

    // S^T = K . Q^T
    f32x4 st[2] = {};
#pragma unroll
    for (int sub = 0; sub < 2; sub++) {
      bf16x8 ka0 = frag16(Ks + (sub * 16 + l16) * 64 + quad * 8);
      bf16x8 ka1 = frag16(Ks + (sub * 16 + l16) * 64 + 32 + quad * 8);
      st[sub] = __builtin_amdgcn_mfma_f32_16x16x32_bf16(ka0, bq0, st[sub], 0, 0, 0);
      st[sub] = __builtin_amdgcn_mfma_f32_16x16x32_bf16(ka1, bq1, st[sub], 0, 0, 0);
    }

    // mask + online softmax (per-lane: q fixed per lane)
    float p[2][4];
    float tm = -1e30f;
#pragma unroll
    for (int sub = 0; sub < 2; sub++)
#pragma unroll
      for (int r = 0; r < 4; r++) {
        const int key = k0 + sub * 16 + quad * 4 + r;
        const float v = (key <= q) ? cl(st[sub][r]) : -1e30f;
        p[sub][r] = v;
        tm = fmaxf(tm, v);
      }
    tm = fmaxf(tm, __shfl_xor(tm, 16));
    tm = fmaxf(tm, __shfl_xor(tm, 32));
    const float newm = fmaxf(m_old, tm);
    const float alpha = exp2f((m_old - newm) * CSCALE);
    m_old = newm;
    float ps = 0.0f;
#pragma unroll
    for (int sub = 0; sub < 2; sub++)
#pragma unroll
      for (int r = 0; r < 4; r++) {
        p[sub][r] = exp2f((p[sub][r] - newm) * CSCALE);
        ps += p[sub][r];
      }
    ps += __shfl_xor(ps, 16);
    ps += __shfl_xor(ps, 32);
    lsum = lsum * alpha + ps;
#pragma unroll
    for (int dc = 0; dc < 4; dc++) o[dc] *= alpha;

    // pack P^T into per-wave [q][keypair] LDS
    {
      u32* pw = Ps32[wave];
#pragma unroll
      for (int sub = 0; sub < 2; sub++)
#pragma unroll
        for (int rp = 0; rp < 2; rp++) {
          const u32 lo = f2bf(p[sub][2 * rp]);
          const u32 hi = f2bf(p[sub][2 * rp + 1]);
          pw[l16 * 16 + sub * 8 + quad * 2 + rp] = lo | (hi << 16);
        }
    }
    __syncthreads();

    // O^T += V^T . P^T
    bf16x8 pb = frag16u(Ps32[wave] + l16 * 16 + quad * 4);
#pragma unroll
    for (int dc = 0; dc < 4; dc++) {
      bf16x8 va = frag16u(Vs32 + (dc * 16 + l16) * 16 + quad * 4);
      o[dc] = __builtin_amdgcn_mfma_f32_16x16x32_bf16(va, pb, o[dc], 0, 0, 0);
    }
  }

  // epilogue: att[bq][t=q][h*64 + d]
  const float inv = 1.0f / lsum;
  const size_t obase = (size_t)(bq * SEQ + q) * EMBED + h * HS;
#pragma unroll
  for (int dc = 0; dc < 4; dc++) {
    u16 sv[4];
#pragma unroll
    for (int r = 0; r < 4; r++) sv[r] = f2bf(cl(o[dc][r] * inv));
    *(u32*)(att + obase + dc * 16 + quad * 4) = (u32)sv[0] | ((u32)sv[1] << 16);
    *(u32*)(att + obase + dc * 16 + quad * 4 + 2) = (u32)sv[2] | ((u32)sv[3] << 16);
  }
}

extern "C" void kernel_launch(void* const* d_in, const int* in_sizes, int n_in,
                              void* d_out, int out_size, void* d_ws,
                              size_t ws_size, hipStream_t stream) {
  const void* x       = d_in[0];
  const void* W_atten = d_in[1];
  const void* b_atten = d_in[2];
  const void* W_proj  = d_in[3];
  const void* b_proj  = d_in[4];

  u16* wt_a = (u16*)d_ws;                         // [3072][1024]
  u16* wt_p = wt_a + (size_t)N_QKV * EMBED;       // [1024][1024]
  u16* ba   = wt_p + (size_t)EMBED * EMBED;       // [3072]
  u16* bp   = ba + N_QKV;                         // [1024]
  u16* xb   = bp + EMBED;                         // [4096][1024]
  u16* qkvb = xb + (size_t)M_TOT * KDIM;          // [4096][3072]
  u16* attb = xb;                                 // alias (stream-ordered)

  convert_kernel<<<(M_TOT * KDIM + 255) / 256, 256, 0, stream>>>(x, xb, M_TOT * KDIM);
  convert_kernel<<<(N_QKV + 255) / 256, 256, 0, stream>>>(b_atten, ba, N_QKV);
  convert_kernel<<<(EMBED + 255) / 256, 256, 0, stream>>>(b_proj, bp, EMBED);
  transpose_conv_kernel<<<dim3(N_QKV / 32, EMBED / 32), dim3(32, 8), 0, stream>>>(
      W_atten, wt_a, EMBED, N_QKV);
  transpose_conv_kernel<<<dim3(EMBED / 32, EMBED / 32), dim3(32, 8), 0, stream>>>(
      W_proj, wt_p, EMBED, EMBED);
  gemm_bt_kernel<false><<<dim3(N_QKV / 128, M_TOT / 128), 256, 0, stream>>>(
      xb, wt_a, ba, (void*)qkvb, N_QKV);
  attn_kernel<<<dim3(SEQ / 64, BATCH * HEADS), 256, 0, stream>>>(
      qkvb, attb);
  gemm_bt_kernel<true><<<dim3(EMBED / 128, M_TOT / 128), 256, 0, stream>>>(
      attb, wt_p, bp, d_out, EMBED);
}

// Round 7
// 452.313 us; speedup vs baseline: 1.1095x; 1.1095x over previous
//
#include <hip/hip_runtime.h>

typedef unsigned short u16;
typedef unsigned int u32;
typedef __bf16 bf16;
typedef bf16 bf16x8 __attribute__((ext_vector_type(8)));
typedef float f32x4 __attribute__((ext_vector_type(4)));
typedef u32 u32x4 __attribute__((ext_vector_type(4)));
typedef u16 u16x4 __attribute__((ext_vector_type(4)));

#define EMBED 1024
#define HEADS 16
#define HS 64
#define BATCH 2
#define SEQ 2048
#define M_TOT (BATCH * SEQ)   // 4096
#define N_QKV (3 * EMBED)     // 3072
#define KDIM  EMBED           // 1024

// softmax scale folded into exp2: (1/sqrt(64)) * log2(e)
#define CSCALE 0.18033688011112042f

__device__ __forceinline__ u16 f2bf(float f) {
  u32 u = __builtin_bit_cast(u32, f);
  u32 r = u + 0x7fffu + ((u >> 16) & 1u);
  return (u16)(r >> 16);
}
__device__ __forceinline__ float bf2f(u16 h) {
  return __builtin_bit_cast(float, (u32)h << 16);
}
__device__ __forceinline__ bf16x8 frag16(const u16* p) {
  return __builtin_bit_cast(bf16x8, *(const u32x4*)p);
}
__device__ __forceinline__ bf16x8 frag16u(const u32* p) {
  return __builtin_bit_cast(bf16x8, *(const u32x4*)p);
}
__device__ __forceinline__ float cl(float v) {
  return fminf(fmaxf(v, -3.0e4f), 3.0e4f);
}

// async global->LDS, 16B per lane (m97 pattern). LDS dest must be lane-linear.
typedef __attribute__((address_space(1))) void gvoid;
typedef __attribute__((address_space(3))) void lvoid;
__device__ __forceinline__ void glds16(const u16* g, u16* l) {
  __builtin_amdgcn_global_load_lds((gvoid*)g, (lvoid*)l, 16, 0, 0);
}

// ---- input dtype detection (f32 vs bf16); inputs confirmed f32 ----
__device__ bool detect_bf16(const u32* p) {
  int ok = 0;
#pragma unroll 1
  for (int i = 0; i < 256; i++) {
    u32 w = p[i];
    u32 e = (w >> 7) & 0xFFu;
    ok += ((e >= 90u) && (e <= 150u)) || ((w & 0x7FFFu) == 0u) ? 1 : 0;
  }
  return ok == 256;
}

__global__ __launch_bounds__(256) void convert_kernel(
    const void* __restrict__ in, u16* __restrict__ out, int n) {
  __shared__ int s_isbf;
  if (threadIdx.x == 0) s_isbf = detect_bf16((const u32*)in) ? 1 : 0;
  __syncthreads();
  const bool isbf = (s_isbf != 0);
  const int i = blockIdx.x * 256 + threadIdx.x;
  if (i < n)
    out[i] = isbf ? ((const u16*)in)[i] : f2bf(((const float*)in)[i]);
}

__global__ __launch_bounds__(256) void transpose_conv_kernel(
    const void* __restrict__ in, u16* __restrict__ out, int R, int C) {
  __shared__ u16 tile[32][33];
  __shared__ int s_isbf;
  if (threadIdx.x == 0 && threadIdx.y == 0)
    s_isbf = detect_bf16((const u32*)in) ? 1 : 0;
  __syncthreads();
  const bool isbf = (s_isbf != 0);
  const int c0 = blockIdx.x * 32;
  const int r0 = blockIdx.y * 32;
  const int tx = threadIdx.x;
  const int ty = threadIdx.y;
#pragma unroll
  for (int i = 0; i < 32; i += 8) {
    const size_t idx = (size_t)(r0 + ty + i) * C + c0 + tx;
    tile[ty + i][tx] = isbf ? ((const u16*)in)[idx] : f2bf(((const float*)in)[idx]);
  }
  __syncthreads();
#pragma unroll
  for (int i = 0; i < 32; i += 8)
    out[(size_t)(c0 + ty + i) * R + r0 + tx] = tile[tx][ty + i];
}

// ============ GEMM qkv: xb[4096,1024] @ wt_a[3072,1024]^T + bias ============
// Epilogue: k,q chunks -> kq[4096][2048]; v chunk -> vt[(bq*1024+hd)][2048] (V^T)
__global__ __launch_bounds__(256) void gemm_qkv_kernel(
    const u16* __restrict__ A, const u16* __restrict__ wt,
    const u16* __restrict__ bias, u16* __restrict__ kq, u16* __restrict__ vt) {
  __shared__ u16 As[128 * 32];
  __shared__ u16 Bs[128 * 32];
  const int tid = threadIdx.x;
  const int lane = tid & 63;
  const int wave = tid >> 6;
  const int quad = lane >> 4;
  const int l16 = lane & 15;
  const int wr = wave >> 1;
  const int wc = wave & 1;
  const int m0 = blockIdx.y * 128;
  const int n0 = blockIdx.x * 128;

  f32x4 acc[4][4] = {};
  const int grow = tid >> 2;
  const int gcol = (tid & 3) * 8;

  for (int k0 = 0; k0 < KDIM; k0 += 32) {
    __syncthreads();
    glds16(A + (size_t)(m0 + grow) * KDIM + k0 + gcol, As + tid * 8);
    glds16(A + (size_t)(m0 + grow + 64) * KDIM + k0 + gcol, As + 2048 + tid * 8);
    glds16(wt + (size_t)(n0 + grow) * KDIM + k0 + gcol, Bs + tid * 8);
    glds16(wt + (size_t)(n0 + grow + 64) * KDIM + k0 + gcol, Bs + 2048 + tid * 8);
    __syncthreads();

    bf16x8 af[4], bfr[4];
#pragma unroll
    for (int i = 0; i < 4; i++) {
      af[i]  = frag16(As + (wr * 64 + i * 16 + l16) * 32 + quad * 8);
      bfr[i] = frag16(Bs + (wc * 64 + i * 16 + l16) * 32 + quad * 8);
    }
#pragma unroll
    for (int mi = 0; mi < 4; mi++)
#pragma unroll
      for (int ni = 0; ni < 4; ni++)
        acc[mi][ni] = __builtin_amdgcn_mfma_f32_16x16x32_bf16(
            af[mi], bfr[ni], acc[mi][ni], 0, 0, 0);
  }

#pragma unroll
  for (int ni = 0; ni < 4; ni++) {
    const int n = n0 + wc * 64 + ni * 16 + l16;
    const float bv = bf2f(bias[n]);
    if (n < 2 * EMBED) {
#pragma unroll
      for (int mi = 0; mi < 4; mi++)
#pragma unroll
        for (int r = 0; r < 4; r++) {
          const int m = m0 + wr * 64 + mi * 16 + quad * 4 + r;
          kq[(size_t)m * 2048 + n] = f2bf(cl(acc[mi][ni][r] + bv));
        }
    } else {
      const int hd = n - 2 * EMBED;   // h*64+d
#pragma unroll
      for (int mi = 0; mi < 4; mi++) {
        const int mbase = m0 + wr * 64 + mi * 16 + quad * 4;
        const int bqi = mbase >> 11;
        const int t0 = mbase & 2047;
        u16x4 pk;
#pragma unroll
        for (int r = 0; r < 4; r++) pk[r] = f2bf(cl(acc[mi][ni][r] + bv));
        *(u16x4*)(vt + ((size_t)bqi * EMBED + hd) * SEQ + t0) = pk;
      }
    }
  }
}

// ============ GEMM proj: attb[4096,1024] @ wt_p[1024,1024]^T + bias -> f32 ==
__global__ __launch_bounds__(256) void gemm_proj_kernel(
    const u16* __restrict__ A, const u16* __restrict__ wt,
    const u16* __restrict__ bias, float* __restrict__ out) {
  __shared__ u16 As[128 * 32];
  __shared__ u16 Bs[128 * 32];
  const int tid = threadIdx.x;
  const int lane = tid & 63;
  const int wave = tid >> 6;
  const int quad = lane >> 4;
  const int l16 = lane & 15;
  const int wr = wave >> 1;
  const int wc = wave & 1;
  const int m0 = blockIdx.y * 128;
  const int n0 = blockIdx.x * 128;

  f32x4 acc[4][4] = {};
  const int grow = tid >> 2;
  const int gcol = (tid & 3) * 8;

  for (int k0 = 0; k0 < KDIM; k0 += 32) {
    __syncthreads();
    glds16(A + (size_t)(m0 + grow) * KDIM + k0 + gcol, As + tid * 8);
    glds16(A + (size_t)(m0 + grow + 64) * KDIM + k0 + gcol, As + 2048 + tid * 8);
    glds16(wt + (size_t)(n0 + grow) * KDIM + k0 + gcol, Bs + tid * 8);
    glds16(wt + (size_t)(n0 + grow + 64) * KDIM + k0 + gcol, Bs + 2048 + tid * 8);
    __syncthreads();

    bf16x8 af[4], bfr[4];
#pragma unroll
    for (int i = 0; i < 4; i++) {
      af[i]  = frag16(As + (wr * 64 + i * 16 + l16) * 32 + quad * 8);
      bfr[i] = frag16(Bs + (wc * 64 + i * 16 + l16) * 32 + quad * 8);
    }
#pragma unroll
    for (int mi = 0; mi < 4; mi++)
#pragma unroll
      for (int ni = 0; ni < 4; ni++)
        acc[mi][ni] = __builtin_amdgcn_mfma_f32_16x16x32_bf16(
            af[mi], bfr[ni], acc[mi][ni], 0, 0, 0);
  }

#pragma unroll
  for (int ni = 0; ni < 4; ni++) {
    const int n = n0 + wc * 64 + ni * 16 + l16;
    const float bv = bf2f(bias[n]);
#pragma unroll
    for (int mi = 0; mi < 4; mi++)
#pragma unroll
      for (int r = 0; r < 4; r++) {
        const int m = m0 + wr * 64 + mi * 16 + quad * 4 + r;
        out[(size_t)m * EMBED + n] = cl(acc[mi][ni][r] + bv);
      }
  }
}

// ============ flash attention (S^T/O^T), causal, 64-key tiles ==============
// kq [4096][2048]: k=[0,1024) q=[1024,2048). vt [bq*1024+hd][2048] = V^T.
// LDS rows padded to 72 u16 / 36 u32 (144B, 16B-aligned, bank-offset 4 -> 2-way).
#define KSP 72
#define PSP 36
__global__ __launch_bounds__(256) void attn_kernel(
    const u16* __restrict__ kq, const u16* __restrict__ vt,
    u16* __restrict__ att) {
  __shared__ u16 Ks[64 * KSP];     // [key][d]
  __shared__ u16 Vts[64 * KSP];    // [d][key]
  __shared__ u32 Ps32[4][16 * PSP]; // per-wave: [q][keypair]

  const int tid = threadIdx.x;
  const int lane = tid & 63;
  const int wave = tid >> 6;
  const int quad = lane >> 4;
  const int l16 = lane & 15;

  const int qt = blockIdx.x;        // 0..31
  const int bh = blockIdx.y;        // 0..31
  const int q0 = qt * 64;
  const int bq = bh >> 4;
  const int h = bh & 15;

  const int q = q0 + wave * 16 + l16;
  const size_t qrow = (size_t)(bq * SEQ + q) * 2048 + EMBED + h * HS;

  bf16x8 bq0 = frag16(kq + qrow + quad * 8);
  bf16x8 bq1 = frag16(kq + qrow + 32 + quad * 8);

  float m_old = -1e30f, lsum = 0.0f;
  f32x4 o[4] = {};   // O^T C-layout: row=d(dc*16+quad*4+r), col=q(l16)

  const int srow = tid >> 3;        // 0..31
  const int scol = (tid & 7) * 8;   // 0..56

  const int nkt = qt + 1;
  for (int kt = 0; kt < nkt; kt++) {
    const int k0 = kt * 64;
    __syncthreads();
    // stage K [64 keys][64 d] (2x16B/thread) and V^T [64 d][64 keys]
    *(u32x4*)(Ks + srow * KSP + scol) =
        *(const u32x4*)(kq + (size_t)(bq * SEQ + k0 + srow) * 2048 + h * HS + scol);
    *(u32x4*)(Ks + (srow + 32) * KSP + scol) =
        *(const u32x4*)(kq + (size_t)(bq * SEQ + k0 + srow + 32) * 2048 + h * HS + scol);
    *(u32x4*)(Vts + srow * KSP + scol) =
        *(const u32x4*)(vt + ((size_t)bq * EMBED + h * HS + srow) * SEQ + k0 + scol);
    *(u32x4*)(Vts + (srow + 32) * KSP + scol) =
        *(const u32x4*)(vt + ((size_t)bq * EMBED + h * HS + srow + 32) * SEQ + k0 + scol);
    __syncthreads();

    // S^T = K . Q^T : 4 key-subtiles x 2 d-chunks
    f32x4 st[4] = {};
#pragma unroll
    for (int sub = 0; sub < 4; sub++) {
      bf16x8 ka0 = frag16(Ks + (sub * 16 + l16) * KSP + quad * 8);
      bf16x8 ka1 = frag16(Ks + (sub * 16 + l16) * KSP + 32 + quad * 8);
      st[sub] = __builtin_amdgcn_mfma_f32_16x16x32_bf16(ka0, bq0, st[sub], 0, 0, 0);
      st[sub] = __builtin_amdgcn_mfma_f32_16x16x32_bf16(ka1, bq1, st[sub], 0, 0, 0);
    }

    // mask + online softmax (per-lane scalar: q fixed per lane)
    float p[4][4];
    float tm = -1e30f;
#pragma unroll
    for (int sub = 0; sub < 4; sub++)
#pragma unroll
      for (int r = 0; r < 4; r++) {
        const int key = k0 + sub * 16 + quad * 4 + r;
        const float v = (key <= q) ? cl(st[sub][r]) : -1e30f;
        p[sub][r] = v;
        tm = fmaxf(tm, v);
      }
    tm = fmaxf(tm, __shfl_xor(tm, 16));
    tm = fmaxf(tm, __shfl_xor(tm, 32));
    const float newm = fmaxf(m_old, tm);
    const float alpha = exp2f((m_old - newm) * CSCALE);
    m_old = newm;
    float ps = 0.0f;
#pragma unroll
    for (int sub = 0; sub < 4; sub++)
#pragma unroll
      for (int r = 0; r < 4; r++) {
        p[sub][r] = exp2f((p[sub][r] - newm) * CSCALE);
        ps += p[sub][r];
      }
    ps += __shfl_xor(ps, 16);
    ps += __shfl_xor(ps, 32);
    lsum = lsum * alpha + ps;
#pragma unroll
    for (int dc = 0; dc < 4; dc++) o[dc] *= alpha;

    // pack P^T into per-wave [q][keypair] LDS (no barrier: same-wave DS order)
    {
      u32* pw = Ps32[wave];
#pragma unroll
      for (int sub = 0; sub < 4; sub++)
#pragma unroll
        for (int rp = 0; rp < 2; rp++) {
          const u32 lo = f2bf(p[sub][2 * rp]);
          const u32 hi = f2bf(p[sub][2 * rp + 1]);
          pw[l16 * PSP + sub * 8 + quad * 2 + rp] = lo | (hi << 16);
        }
    }

    // O^T += V^T . P^T : 2 key-chunks of 32
#pragma unroll
    for (int kc = 0; kc < 2; kc++) {
      bf16x8 pb = frag16u(Ps32[wave] + l16 * PSP + kc * 16 + quad * 4);
#pragma unroll
      for (int dc = 0; dc < 4; dc++) {
        bf16x8 va = frag16(Vts + (dc * 16 + l16) * KSP + kc * 32 + quad * 8);
        o[dc] = __builtin_amdgcn_mfma_f32_16x16x32_bf16(va, pb, o[dc], 0, 0, 0);
      }
    }
  }

  // epilogue: att[bq][t=q][h*64 + d]
  const float inv = 1.0f / lsum;
  const size_t obase = (size_t)(bq * SEQ + q) * EMBED + h * HS;
#pragma unroll
  for (int dc = 0; dc < 4; dc++) {
    u16 sv[4];
#pragma unroll
    for (int r = 0; r < 4; r++) sv[r] = f2bf(cl(o[dc][r] * inv));
    *(u32*)(att + obase + dc * 16 + quad * 4) = (u32)sv[0] | ((u32)sv[1] << 16);
    *(u32*)(att + obase + dc * 16 + quad * 4 + 2) = (u32)sv[2] | ((u32)sv[3] << 16);
  }
}

extern "C" void kernel_launch(void* const* d_in, const int* in_sizes, int n_in,
                              void* d_out, int out_size, void* d_ws,
                              size_t ws_size, hipStream_t stream) {
  const void* x       = d_in[0];
  const void* W_atten = d_in[1];
  const void* b_atten = d_in[2];
  const void* W_proj  = d_in[3];
  const void* b_proj  = d_in[4];

  // workspace (u16 units), total 41.95 MB (same as r6's proven budget)
  u16* wt_a = (u16*)d_ws;                         // [3072][1024]
  u16* wt_p = wt_a + (size_t)N_QKV * EMBED;       // [1024][1024]
  u16* ba   = wt_p + (size_t)EMBED * EMBED;       // [3072]
  u16* bp   = ba + N_QKV;                         // [1024]
  u16* xb   = bp + EMBED;                         // [4096][1024]
  u16* kq   = xb + (size_t)M_TOT * KDIM;          // [4096][2048]
  u16* vt   = kq + (size_t)M_TOT * 2048;          // [2*1024][2048]
  u16* attb = xb;                                 // alias (xb dead after qkv GEMM)

  convert_kernel<<<(M_TOT * KDIM + 255) / 256, 256, 0, stream>>>(x, xb, M_TOT * KDIM);
  convert_kernel<<<(N_QKV + 255) / 256, 256, 0, stream>>>(b_atten, ba, N_QKV);
  convert_kernel<<<(EMBED + 255) / 256, 256, 0, stream>>>(b_proj, bp, EMBED);
  transpose_conv_kernel<<<dim3(N_QKV / 32, EMBED / 32), dim3(32, 8), 0, stream>>>(
      W_atten, wt_a, EMBED, N_QKV);
  transpose_conv_kernel<<<dim3(EMBED / 32, EMBED / 32), dim3(32, 8), 0, stream>>>(
      W_proj, wt_p, EMBED, EMBED);
  gemm_qkv_kernel<<<dim3(N_QKV / 128, M_TOT / 128), 256, 0, stream>>>(
      xb, wt_a, ba, kq, vt);
  attn_kernel<<<dim3(SEQ / 64, BATCH * HEADS), 256, 0, stream>>>(
      kq, vt, attb);
  gemm_proj_kernel<<<dim3(EMBED / 128, M_TOT / 128), 256, 0, stream>>>(
      attb, wt_p, bp, (float*)d_out);
}

// Round 8
// 259.097 us; speedup vs baseline: 1.9369x; 1.7457x over previous
//
#include <hip/hip_runtime.h>

typedef unsigned short u16;
typedef unsigned int u32;
typedef __bf16 bf16;
typedef bf16 bf16x8 __attribute__((ext_vector_type(8)));
typedef float f32x4 __attribute__((ext_vector_type(4)));
typedef u32 u32x4 __attribute__((ext_vector_type(4)));
typedef u16 u16x4 __attribute__((ext_vector_type(4)));

#define EMBED 1024
#define HEADS 16
#define HS 64
#define BATCH 2
#define SEQ 2048
#define M_TOT (BATCH * SEQ)   // 4096
#define N_QKV (3 * EMBED)     // 3072
#define KDIM  EMBED           // 1024

// softmax scale folded into exp2: (1/sqrt(64)) * log2(e)
#define CSCALE 0.18033688011112042f

__device__ __forceinline__ u16 f2bf(float f) {
  u32 u = __builtin_bit_cast(u32, f);
  u32 r = u + 0x7fffu + ((u >> 16) & 1u);
  return (u16)(r >> 16);
}
__device__ __forceinline__ float bf2f(u16 h) {
  return __builtin_bit_cast(float, (u32)h << 16);
}
__device__ __forceinline__ bf16x8 frag16(const u16* p) {
  return __builtin_bit_cast(bf16x8, *(const u32x4*)p);
}
__device__ __forceinline__ bf16x8 frag16u(const u32* p) {
  return __builtin_bit_cast(bf16x8, *(const u32x4*)p);
}
__device__ __forceinline__ float cl(float v) {
  return fminf(fmaxf(v, -3.0e4f), 3.0e4f);
}

// async global->LDS, 16B per lane (m97 pattern). LDS dest must be lane-linear.
typedef __attribute__((address_space(1))) void gvoid;
typedef __attribute__((address_space(3))) void lvoid;
__device__ __forceinline__ void glds16(const u16* g, u16* l) {
  __builtin_amdgcn_global_load_lds((gvoid*)g, (lvoid*)l, 16, 0, 0);
}

// ---- convert f32 -> bf16, vectorized (inputs confirmed f32; r3->r4 proof) ----
__global__ __launch_bounds__(256) void convert_kernel(
    const float* __restrict__ in, u16* __restrict__ out, int n4) {
  const int i = blockIdx.x * 256 + threadIdx.x;
  if (i < n4) {
    f32x4 v = *(const f32x4*)(in + (size_t)i * 4);
    u16x4 pk;
#pragma unroll
    for (int j = 0; j < 4; j++) pk[j] = f2bf(v[j]);
    *(u16x4*)(out + (size_t)i * 4) = pk;
  }
}

// ---- transpose + convert: in [R][C] f32 -> out [C][R] bf16 ----
__global__ __launch_bounds__(256) void transpose_conv_kernel(
    const float* __restrict__ in, u16* __restrict__ out, int R, int C) {
  __shared__ u16 tile[32][33];
  const int c0 = blockIdx.x * 32;
  const int r0 = blockIdx.y * 32;
  const int tx = threadIdx.x;
  const int ty = threadIdx.y;
#pragma unroll
  for (int i = 0; i < 32; i += 8)
    tile[ty + i][tx] = f2bf(in[(size_t)(r0 + ty + i) * C + c0 + tx]);
  __syncthreads();
#pragma unroll
  for (int i = 0; i < 32; i += 8)
    out[(size_t)(c0 + ty + i) * R + r0 + tx] = tile[tx][ty + i];
}

// ============ GEMM qkv: xb[4096,1024] @ wt_a[3072,1024]^T + bias ============
// Epilogue: k,q chunks -> kq[4096][2048]; v chunk -> vt[(bq*1024+hd)][2048] (V^T)
__global__ __launch_bounds__(256) void gemm_qkv_kernel(
    const u16* __restrict__ A, const u16* __restrict__ wt,
    const u16* __restrict__ bias, u16* __restrict__ kq, u16* __restrict__ vt) {
  __shared__ u16 As[128 * 32];
  __shared__ u16 Bs[128 * 32];
  const int tid = threadIdx.x;
  const int lane = tid & 63;
  const int wave = tid >> 6;
  const int quad = lane >> 4;
  const int l16 = lane & 15;
  const int wr = wave >> 1;
  const int wc = wave & 1;
  const int m0 = blockIdx.y * 128;
  const int n0 = blockIdx.x * 128;

  f32x4 acc[4][4] = {};
  const int grow = tid >> 2;
  const int gcol = (tid & 3) * 8;

  for (int k0 = 0; k0 < KDIM; k0 += 32) {
    __syncthreads();
    glds16(A + (size_t)(m0 + grow) * KDIM + k0 + gcol, As + tid * 8);
    glds16(A + (size_t)(m0 + grow + 64) * KDIM + k0 + gcol, As + 2048 + tid * 8);
    glds16(wt + (size_t)(n0 + grow) * KDIM + k0 + gcol, Bs + tid * 8);
    glds16(wt + (size_t)(n0 + grow + 64) * KDIM + k0 + gcol, Bs + 2048 + tid * 8);
    __syncthreads();

    bf16x8 af[4], bfr[4];
#pragma unroll
    for (int i = 0; i < 4; i++) {
      af[i]  = frag16(As + (wr * 64 + i * 16 + l16) * 32 + quad * 8);
      bfr[i] = frag16(Bs + (wc * 64 + i * 16 + l16) * 32 + quad * 8);
    }
#pragma unroll
    for (int mi = 0; mi < 4; mi++)
#pragma unroll
      for (int ni = 0; ni < 4; ni++)
        acc[mi][ni] = __builtin_amdgcn_mfma_f32_16x16x32_bf16(
            af[mi], bfr[ni], acc[mi][ni], 0, 0, 0);
  }

#pragma unroll
  for (int ni = 0; ni < 4; ni++) {
    const int n = n0 + wc * 64 + ni * 16 + l16;
    const float bv = bf2f(bias[n]);
    if (n < 2 * EMBED) {
#pragma unroll
      for (int mi = 0; mi < 4; mi++)
#pragma unroll
        for (int r = 0; r < 4; r++) {
          const int m = m0 + wr * 64 + mi * 16 + quad * 4 + r;
          kq[(size_t)m * 2048 + n] = f2bf(cl(acc[mi][ni][r] + bv));
        }
    } else {
      const int hd = n - 2 * EMBED;   // h*64+d
#pragma unroll
      for (int mi = 0; mi < 4; mi++) {
        const int mbase = m0 + wr * 64 + mi * 16 + quad * 4;
        const int bqi = mbase >> 11;
        const int t0 = mbase & 2047;
        u16x4 pk;
#pragma unroll
        for (int r = 0; r < 4; r++) pk[r] = f2bf(cl(acc[mi][ni][r] + bv));
        *(u16x4*)(vt + ((size_t)bqi * EMBED + hd) * SEQ + t0) = pk;
      }
    }
  }
}

// ============ GEMM proj: attb[4096,1024] @ wt_p[1024,1024]^T + bias -> f32 ==
__global__ __launch_bounds__(256) void gemm_proj_kernel(
    const u16* __restrict__ A, const u16* __restrict__ wt,
    const u16* __restrict__ bias, float* __restrict__ out) {
  __shared__ u16 As[128 * 32];
  __shared__ u16 Bs[128 * 32];
  const int tid = threadIdx.x;
  const int lane = tid & 63;
  const int wave = tid >> 6;
  const int quad = lane >> 4;
  const int l16 = lane & 15;
  const int wr = wave >> 1;
  const int wc = wave & 1;
  const int m0 = blockIdx.y * 128;
  const int n0 = blockIdx.x * 128;

  f32x4 acc[4][4] = {};
  const int grow = tid >> 2;
  const int gcol = (tid & 3) * 8;

  for (int k0 = 0; k0 < KDIM; k0 += 32) {
    __syncthreads();
    glds16(A + (size_t)(m0 + grow) * KDIM + k0 + gcol, As + tid * 8);
    glds16(A + (size_t)(m0 + grow + 64) * KDIM + k0 + gcol, As + 2048 + tid * 8);
    glds16(wt + (size_t)(n0 + grow) * KDIM + k0 + gcol, Bs + tid * 8);
    glds16(wt + (size_t)(n0 + grow + 64) * KDIM + k0 + gcol, Bs + 2048 + tid * 8);
    __syncthreads();

    bf16x8 af[4], bfr[4];
#pragma unroll
    for (int i = 0; i < 4; i++) {
      af[i]  = frag16(As + (wr * 64 + i * 16 + l16) * 32 + quad * 8);
      bfr[i] = frag16(Bs + (wc * 64 + i * 16 + l16) * 32 + quad * 8);
    }
#pragma unroll
    for (int mi = 0; mi < 4; mi++)
#pragma unroll
      for (int ni = 0; ni < 4; ni++)
        acc[mi][ni] = __builtin_amdgcn_mfma_f32_16x16x32_bf16(
            af[mi], bfr[ni], acc[mi][ni], 0, 0, 0);
  }

#pragma unroll
  for (int ni = 0; ni < 4; ni++) {
    const int n = n0 + wc * 64 + ni * 16 + l16;
    const float bv = bf2f(bias[n]);
#pragma unroll
    for (int mi = 0; mi < 4; mi++)
#pragma unroll
      for (int r = 0; r < 4; r++) {
        const int m = m0 + wr * 64 + mi * 16 + quad * 4 + r;
        out[(size_t)m * EMBED + n] = cl(acc[mi][ni][r] + bv);
      }
  }
}

// ============ flash attention (S^T/O^T), causal, 64-key tiles ==============
// kq [4096][2048]: k=[0,1024) q=[1024,2048). vt [bq*1024+hd][2048] = V^T.
// LDS rows padded to 72 u16 / 36 u32 (144B, 16B-aligned, bank-offset 4 -> 2-way).
#define KSP 72
#define PSP 36
__global__ __launch_bounds__(256) void attn_kernel(
    const u16* __restrict__ kq, const u16* __restrict__ vt,
    u16* __restrict__ att) {
  __shared__ u16 Ks[64 * KSP];      // [key][d]
  __shared__ u16 Vts[64 * KSP];     // [d][key]
  __shared__ u32 Ps32[4][16 * PSP]; // per-wave: [q][keypair]

  const int tid = threadIdx.x;
  const int lane = tid & 63;
  const int wave = tid >> 6;
  const int quad = lane >> 4;
  const int l16 = lane & 15;

  // heavy tiles (large qt => many key tiles) dispatch first
  const int qt = (gridDim.x - 1) - blockIdx.x;   // 0..31
  const int bh = blockIdx.y;        // 0..31
  const int q0 = qt * 64;
  const int bq = bh >> 4;
  const int h = bh & 15;

  const int q = q0 + wave * 16 + l16;
  const size_t qrow = (size_t)(bq * SEQ + q) * 2048 + EMBED + h * HS;

  bf16x8 bq0 = frag16(kq + qrow + quad * 8);
  bf16x8 bq1 = frag16(kq + qrow + 32 + quad * 8);

  float m_old = -1e30f, lsum = 0.0f;
  f32x4 o[4] = {};   // O^T C-layout: row=d(dc*16+quad*4+r), col=q(l16)

  const int srow = tid >> 3;        // 0..31
  const int scol = (tid & 7) * 8;   // 0..56

  const int nkt = qt + 1;
  for (int kt = 0; kt < nkt; kt++) {
    const int k0 = kt * 64;
    __syncthreads();
    // stage K [64 keys][64 d] (2x16B/thread) and V^T [64 d][64 keys]
    *(u32x4*)(Ks + srow * KSP + scol) =
        *(const u32x4*)(kq + (size_t)(bq * SEQ + k0 + srow) * 2048 + h * HS + scol);
    *(u32x4*)(Ks + (srow + 32) * KSP + scol) =
        *(const u32x4*)(kq + (size_t)(bq * SEQ + k0 + srow + 32) * 2048 + h * HS + scol);
    *(u32x4*)(Vts + srow * KSP + scol) =
        *(const u32x4*)(vt + ((size_t)bq * EMBED + h * HS + srow) * SEQ + k0 + scol);
    *(u32x4*)(Vts + (srow + 32) * KSP + scol) =
        *(const u32x4*)(vt + ((size_t)bq * EMBED + h * HS + srow + 32) * SEQ + k0 + scol);
    __syncthreads();

    // S^T = K . Q^T : 4 key-subtiles x 2 d-chunks
    f32x4 st[4] = {};
#pragma unroll
    for (int sub = 0; sub < 4; sub++) {
      bf16x8 ka0 = frag16(Ks + (sub * 16 + l16) * KSP + quad * 8);
      bf16x8 ka1 = frag16(Ks + (sub * 16 + l16) * KSP + 32 + quad * 8);
      st[sub] = __builtin_amdgcn_mfma_f32_16x16x32_bf16(ka0, bq0, st[sub], 0, 0, 0);
      st[sub] = __builtin_amdgcn_mfma_f32_16x16x32_bf16(ka1, bq1, st[sub], 0, 0, 0);
    }

    // mask + online softmax (per-lane scalar: q fixed per lane)
    float p[4][4];
    float tm = -1e30f;
#pragma unroll
    for (int sub = 0; sub < 4; sub++)
#pragma unroll
      for (int r = 0; r < 4; r++) {
        const int key = k0 + sub * 16 + quad * 4 + r;
        const float v = (key <= q) ? cl(st[sub][r]) : -1e30f;
        p[sub][r] = v;
        tm = fmaxf(tm, v);
      }
    tm = fmaxf(tm, __shfl_xor(tm, 16));
    tm = fmaxf(tm, __shfl_xor(tm, 32));
    const float newm = fmaxf(m_old, tm);
    const float alpha = exp2f((m_old - newm) * CSCALE);
    m_old = newm;
    float ps = 0.0f;
#pragma unroll
    for (int sub = 0; sub < 4; sub++)
#pragma unroll
      for (int r = 0; r < 4; r++) {
        p[sub][r] = exp2f((p[sub][r] - newm) * CSCALE);
        ps += p[sub][r];
      }
    ps += __shfl_xor(ps, 16);
    ps += __shfl_xor(ps, 32);
    lsum = lsum * alpha + ps;
#pragma unroll
    for (int dc = 0; dc < 4; dc++) o[dc] *= alpha;

    // pack P^T into per-wave [q][keypair] LDS (no barrier: same-wave DS order)
    {
      u32* pw = Ps32[wave];
#pragma unroll
      for (int sub = 0; sub < 4; sub++)
#pragma unroll
        for (int rp = 0; rp < 2; rp++) {
          const u32 lo = f2bf(p[sub][2 * rp]);
          const u32 hi = f2bf(p[sub][2 * rp + 1]);
          pw[l16 * PSP + sub * 8 + quad * 2 + rp] = lo | (hi << 16);
        }
    }

    // O^T += V^T . P^T : 2 key-chunks of 32
#pragma unroll
    for (int kc = 0; kc < 2; kc++) {
      bf16x8 pb = frag16u(Ps32[wave] + l16 * PSP + kc * 16 + quad * 4);
#pragma unroll
      for (int dc = 0; dc < 4; dc++) {
        bf16x8 va = frag16(Vts + (dc * 16 + l16) * KSP + kc * 32 + quad * 8);
        o[dc] = __builtin_amdgcn_mfma_f32_16x16x32_bf16(va, pb, o[dc], 0, 0, 0);
      }
    }
  }

  // epilogue: att[bq][t=q][h*64 + d]
  const float inv = 1.0f / lsum;
  const size_t obase = (size_t)(bq * SEQ + q) * EMBED + h * HS;
#pragma unroll
  for (int dc = 0; dc < 4; dc++) {
    u16 sv[4];
#pragma unroll
    for (int r = 0; r < 4; r++) sv[r] = f2bf(cl(o[dc][r] * inv));
    *(u32*)(att + obase + dc * 16 + quad * 4) = (u32)sv[0] | ((u32)sv[1] << 16);
    *(u32*)(att + obase + dc * 16 + quad * 4 + 2) = (u32)sv[2] | ((u32)sv[3] << 16);
  }
}

extern "C" void kernel_launch(void* const* d_in, const int* in_sizes, int n_in,
                              void* d_out, int out_size, void* d_ws,
                              size_t ws_size, hipStream_t stream) {
  const float* x       = (const float*)d_in[0];
  const float* W_atten = (const float*)d_in[1];
  const float* b_atten = (const float*)d_in[2];
  const float* W_proj  = (const float*)d_in[3];
  const float* b_proj  = (const float*)d_in[4];

  // workspace (u16 units), total 41.95 MB
  u16* wt_a = (u16*)d_ws;                         // [3072][1024]
  u16* wt_p = wt_a + (size_t)N_QKV * EMBED;       // [1024][1024]
  u16* ba   = wt_p + (size_t)EMBED * EMBED;       // [3072]
  u16* bp   = ba + N_QKV;                         // [1024]
  u16* xb   = bp + EMBED;                         // [4096][1024]
  u16* kq   = xb + (size_t)M_TOT * KDIM;          // [4096][2048]
  u16* vt   = kq + (size_t)M_TOT * 2048;          // [2*1024][2048]
  u16* attb = xb;                                 // alias (xb dead after qkv GEMM)

  convert_kernel<<<(M_TOT * KDIM / 4 + 255) / 256, 256, 0, stream>>>(
      x, xb, M_TOT * KDIM / 4);
  convert_kernel<<<(N_QKV / 4 + 255) / 256, 256, 0, stream>>>(b_atten, ba, N_QKV / 4);
  convert_kernel<<<(EMBED / 4 + 255) / 256, 256, 0, stream>>>(b_proj, bp, EMBED / 4);
  transpose_conv_kernel<<<dim3(N_QKV / 32, EMBED / 32), dim3(32, 8), 0, stream>>>(
      W_atten, wt_a, EMBED, N_QKV);
  transpose_conv_kernel<<<dim3(EMBED / 32, EMBED / 32), dim3(32, 8), 0, stream>>>(
      W_proj, wt_p, EMBED, EMBED);
  gemm_qkv_kernel<<<dim3(N_QKV / 128, M_TOT / 128), 256, 0, stream>>>(
      xb, wt_a, ba, kq, vt);
  attn_kernel<<<dim3(SEQ / 64, BATCH * HEADS), 256, 0, stream>>>(
      kq, vt, attb);
  gemm_proj_kernel<<<dim3(EMBED / 128, M_TOT / 128), 256, 0, stream>>>(
      attb, wt_p, bp, (float*)d_out);
}